// Round 1
// baseline (2048.266 us; speedup 1.0000x reference)
//
#include <hip/hip_runtime.h>
#include <math.h>

#define NB    256   // blocks
#define NT    256   // threads per block (4 waves)
#define B_TOT 1024
#define T_TOT 512
#define XT    32    // x time-tile length

__device__ __forceinline__ float rcp_f(float v){ return __builtin_amdgcn_rcpf(v); }
__device__ __forceinline__ float sig_f(float x){ return rcp_f(1.0f + __expf(-x)); }
// tanh via exp; saturates correctly at +/-inf (rcp(inf)=0)
__device__ __forceinline__ float tanh_f(float x){ return 1.0f - 2.0f*rcp_f(__expf(2.0f*x) + 1.0f); }

__global__ __launch_bounds__(NT, 1) void lstm_ac_fused(
    const float* __restrict__ x,
    const float* __restrict__ h0i, const float* __restrict__ c0i,
    const float* __restrict__ wih0, const float* __restrict__ whh0,
    const float* __restrict__ bih0, const float* __restrict__ bhh0,
    const float* __restrict__ wih1, const float* __restrict__ whh1,
    const float* __restrict__ bih1, const float* __restrict__ bhh1,
    const float* __restrict__ wmean, const float* __restrict__ bmean,
    const float* __restrict__ wcrit, const float* __restrict__ bcrit,
    float* __restrict__ out)
{
    const int tid = threadIdx.x;
    const int u   = tid & 63;      // hidden unit (lane)
    const int q   = tid >> 6;      // gate type / wave id / owned-row index
    const int r0  = blockIdx.x * 4;
    const int g   = q * 64 + u;    // gate row in the 256-wide gate dim

    // h state, stored transposed: element k holds {row0,row1,row2,row3}
    __shared__ float4 hA[64];          // layer-0 h
    __shared__ float4 hB[64];          // layer-1 h
    __shared__ float4 xt[5][XT];       // x tile: [i][tt] -> rows 0..3
    __shared__ float  gx[4][4][64];    // activated gates: [row][gate][unit]

    // ---- weights into registers (full unroll => static indices => VGPRs) ----
    float w0[64], w1a[64], w1b[64];
#pragma unroll
    for (int kk = 0; kk < 16; ++kk){
        float4 a = *(const float4*)(whh0 + (size_t)g*64 + kk*4);
        w0 [4*kk+0]=a.x; w0 [4*kk+1]=a.y; w0 [4*kk+2]=a.z; w0 [4*kk+3]=a.w;
        float4 b = *(const float4*)(wih1 + (size_t)g*64 + kk*4);
        w1a[4*kk+0]=b.x; w1a[4*kk+1]=b.y; w1a[4*kk+2]=b.z; w1a[4*kk+3]=b.w;
        float4 c = *(const float4*)(whh1 + (size_t)g*64 + kk*4);
        w1b[4*kk+0]=c.x; w1b[4*kk+1]=c.y; w1b[4*kk+2]=c.z; w1b[4*kk+3]=c.w;
    }
    float xw[5];
#pragma unroll
    for (int i = 0; i < 5; ++i) xw[i] = wih0[g*5 + i];
    const float b0 = bih0[g] + bhh0[g];
    const float b1 = bih1[g] + bhh1[g];

    // ---- state init: this thread owns row (r0+q), unit u ----
    const int rowq = r0 + q;
    float c0own = c0i[rowq*64 + u];                  // c0[0]
    float c1own = c0i[B_TOT*64 + rowq*64 + u];       // c0[1]
    float h1own = h0i[B_TOT*64 + rowq*64 + u];       // h0[1]
    ((float*)&hA[u])[q] = h0i[rowq*64 + u];          // h0[0]
    ((float*)&hB[u])[q] = h1own;
    __syncthreads();

    for (int t = 0; t < T_TOT; ++t){
        const int tt = t & (XT-1);
        if (tt == 0){
            __syncthreads();   // all reads of old tile done
            for (int e = tid; e < 4*XT*5; e += NT){
                int r   = e / (XT*5);
                int rem = e - r*(XT*5);
                int ts  = rem / 5;
                int i   = rem - ts*5;
                ((float*)&xt[i][ts])[r] = x[((size_t)(r0 + r)*T_TOT + (t + ts))*5 + i];
            }
            __syncthreads();
        }

        // ---------- layer 0: gate q pre-activations for rows 0..3 ----------
        float a0 = b0, a1 = b0, a2 = b0, a3 = b0;
#pragma unroll
        for (int i = 0; i < 5; ++i){
            float4 xv = xt[i][tt];
            a0 += xv.x*xw[i]; a1 += xv.y*xw[i]; a2 += xv.z*xw[i]; a3 += xv.w*xw[i];
        }
#pragma unroll
        for (int k = 0; k < 64; ++k){
            float4 hv = hA[k];   // broadcast read (same addr all lanes)
            a0 += hv.x*w0[k]; a1 += hv.y*w0[k]; a2 += hv.z*w0[k]; a3 += hv.w*w0[k];
        }
        if (q == 2){ a0 = tanh_f(a0); a1 = tanh_f(a1); a2 = tanh_f(a2); a3 = tanh_f(a3); }
        else       { a0 = sig_f (a0); a1 = sig_f (a1); a2 = sig_f (a2); a3 = sig_f (a3); }
        gx[0][q][u] = a0; gx[1][q][u] = a1; gx[2][q][u] = a2; gx[3][q][u] = a3;
        __syncthreads();   // B1: gates published

        {   // c0/h0 update for own row q
            float gi = gx[q][0][u], gf = gx[q][1][u], gg = gx[q][2][u], go = gx[q][3][u];
            c0own = gf*c0own + gi*gg;
            float h0n = go * tanh_f(c0own);
            ((float*)&hA[u])[q] = h0n;
        }
        __syncthreads();   // B2: new h0 published

        // ---------- layer 1: K=128 (h0_new via w_ih1, h1 via w_hh1) ----------
        float d0 = b1, d1 = b1, d2 = b1, d3 = b1;
#pragma unroll
        for (int k = 0; k < 64; ++k){
            float4 hv = hA[k];
            d0 += hv.x*w1a[k]; d1 += hv.y*w1a[k]; d2 += hv.z*w1a[k]; d3 += hv.w*w1a[k];
        }
#pragma unroll
        for (int k = 0; k < 64; ++k){
            float4 hv = hB[k];
            d0 += hv.x*w1b[k]; d1 += hv.y*w1b[k]; d2 += hv.z*w1b[k]; d3 += hv.w*w1b[k];
        }
        if (q == 2){ d0 = tanh_f(d0); d1 = tanh_f(d1); d2 = tanh_f(d2); d3 = tanh_f(d3); }
        else       { d0 = sig_f (d0); d1 = sig_f (d1); d2 = sig_f (d2); d3 = sig_f (d3); }
        gx[0][q][u] = d0; gx[1][q][u] = d1; gx[2][q][u] = d2; gx[3][q][u] = d3;
        __syncthreads();   // B3: gates published

        {   // c1/h1 update for own row q
            float gi = gx[q][0][u], gf = gx[q][1][u], gg = gx[q][2][u], go = gx[q][3][u];
            c1own = gf*c1own + gi*gg;
            h1own = go * tanh_f(c1own);
            ((float*)&hB[u])[q] = h1own;
        }
        __syncthreads();   // B4: tail safety (gx WAR across step boundary)
    }

    // ---------- heads on last h1 (thread holds h1[row q][u]) ----------
    float pm = h1own * wmean[u];
    float pc = h1own * wcrit[u];
#pragma unroll
    for (int off = 32; off > 0; off >>= 1){
        pm += __shfl_down(pm, off);
        pc += __shfl_down(pc, off);
    }
    if (u == 0){
        float ml = pm + bmean[0];
        out[rowq]           = 2.0f * tanh_f(ml);                 // mean
        out[B_TOT + rowq]   = __logf(1.0f + __expf(ml));         // log_std = softplus
        out[2*B_TOT + rowq] = pc + bcrit[0];                     // state_value
    }
}

extern "C" void kernel_launch(void* const* d_in, const int* in_sizes, int n_in,
                              void* d_out, int out_size, void* d_ws, size_t ws_size,
                              hipStream_t stream) {
    const float* x     = (const float*)d_in[0];
    const float* h0i   = (const float*)d_in[1];
    const float* c0i   = (const float*)d_in[2];
    const float* wih0  = (const float*)d_in[3];
    const float* whh0  = (const float*)d_in[4];
    const float* bih0  = (const float*)d_in[5];
    const float* bhh0  = (const float*)d_in[6];
    const float* wih1  = (const float*)d_in[7];
    const float* whh1  = (const float*)d_in[8];
    const float* bih1  = (const float*)d_in[9];
    const float* bhh1  = (const float*)d_in[10];
    const float* wmean = (const float*)d_in[11];
    const float* bmean = (const float*)d_in[12];
    const float* wcrit = (const float*)d_in[13];
    const float* bcrit = (const float*)d_in[14];

    lstm_ac_fused<<<NB, NT, 0, stream>>>(x, h0i, c0i, wih0, whh0, bih0, bhh0,
                                         wih1, whh1, bih1, bhh1,
                                         wmean, bmean, wcrit, bcrit,
                                         (float*)d_out);
}

// Round 2
// 1883.931 us; speedup vs baseline: 1.0872x; 1.0872x over previous
//
#include <hip/hip_runtime.h>
#include <math.h>

#define NB    256   // blocks (4 batch rows each)
#define NT    512   // threads per block (8 waves)
#define B_TOT 1024
#define T_TOT 512
#define XT    32    // x time-tile length

__device__ __forceinline__ float rcp_f(float v){ return __builtin_amdgcn_rcpf(v); }
__device__ __forceinline__ float sig_f(float x){ return rcp_f(1.0f + __expf(-x)); }
__device__ __forceinline__ float tanh_f(float x){ return 1.0f - 2.0f*rcp_f(__expf(2.0f*x) + 1.0f); }

__global__ __launch_bounds__(NT, 2) void lstm_ac_fused(
    const float* __restrict__ x,
    const float* __restrict__ h0i, const float* __restrict__ c0i,
    const float* __restrict__ wih0, const float* __restrict__ whh0,
    const float* __restrict__ bih0, const float* __restrict__ bhh0,
    const float* __restrict__ wih1, const float* __restrict__ whh1,
    const float* __restrict__ bih1, const float* __restrict__ bhh1,
    const float* __restrict__ wmean, const float* __restrict__ bmean,
    const float* __restrict__ wcrit, const float* __restrict__ bcrit,
    float* __restrict__ out)
{
    const int tid  = threadIdx.x;
    const int lane = tid & 63;
    const int s    = lane & 31;     // unit-in-group
    const int half = lane >> 5;     // k-half owned by this lane
    const int w    = tid >> 6;      // wave 0..7
    const int q    = w & 3;         // gate type
    const int uh   = w >> 2;        // unit-group (units 32*uh..)
    const int gu   = uh*32 + s;     // hidden unit 0..63
    const int g    = q*64 + gu;     // gate row 0..255
    const int r0   = blockIdx.x * 4;
    const int ro   = 2*half + (q & 1);   // row this thread updates (q and q+2 duplicate)

    __shared__ float4 hA[64];        // layer-0 h, [k] -> rows 0..3
    __shared__ float4 hB[64];        // layer-1 h
    __shared__ float4 xt[5][XT];     // x tile
    __shared__ float  gx[4][4][64];  // activated gates [row][gate][unit]

    // ---- weights: 96 floats/thread, k-split ----
    float w0[32];                    // whh0[g][32*half + j]
#pragma unroll
    for (int j4 = 0; j4 < 8; ++j4){
        float4 a = *(const float4*)(whh0 + (size_t)g*64 + half*32 + j4*4);
        w0[4*j4+0]=a.x; w0[4*j4+1]=a.y; w0[4*j4+2]=a.z; w0[4*j4+3]=a.w;
    }
    float w1[64];                    // half0: wih1[g][j] (acts on hA); half1: whh1[g][j] (acts on hB)
    const float* w1base = half ? whh1 : wih1;
#pragma unroll
    for (int j4 = 0; j4 < 16; ++j4){
        float4 a = *(const float4*)(w1base + (size_t)g*64 + j4*4);
        w1[4*j4+0]=a.x; w1[4*j4+1]=a.y; w1[4*j4+2]=a.z; w1[4*j4+3]=a.w;
    }
    float xw[5];
#pragma unroll
    for (int i = 0; i < 5; ++i) xw[i] = wih0[g*5 + i];
    const float b0 = bih0[g] + bhh0[g];
    const float b1 = bih1[g] + bhh1[g];

    // pin weights in VGPRs: forbid rematerialization/reload
#pragma unroll
    for (int j = 0; j < 32; ++j) asm volatile("" : "+v"(w0[j]));
#pragma unroll
    for (int j = 0; j < 64; ++j) asm volatile("" : "+v"(w1[j]));

    // ---- state init ----
    const int rowg = r0 + ro;
    float cOwn0 = c0i[rowg*64 + gu];
    float cOwn1 = c0i[B_TOT*64 + rowg*64 + gu];
    float hOwn1 = h0i[B_TOT*64 + rowg*64 + gu];
    if (q < 2){
        ((float*)&hA[gu])[ro] = h0i[rowg*64 + gu];
        ((float*)&hB[gu])[ro] = hOwn1;
    }
    __syncthreads();

#pragma unroll 1
    for (int t = 0; t < T_TOT; ++t){
        const int tt = t & (XT-1);
        if (tt == 0){
            // all reads of the old tile finished before prev step's B4
            for (int e = tid; e < 4*XT*5; e += NT){
                int r   = e / (XT*5);
                int rem = e - r*(XT*5);
                int ts  = rem / 5;
                int i   = rem - ts*5;
                ((float*)&xt[i][ts])[r] = x[((size_t)(r0 + r)*T_TOT + (t + ts))*5 + i];
            }
            __syncthreads();
        }

        // ---------- layer 0: partial over this lane's k-half ----------
        float a0, a1, a2, a3;
        if (!half){
            a0 = b0; a1 = b0; a2 = b0; a3 = b0;
#pragma unroll
            for (int i = 0; i < 5; ++i){
                float4 xv = xt[i][tt];
                a0 += xv.x*xw[i]; a1 += xv.y*xw[i]; a2 += xv.z*xw[i]; a3 += xv.w*xw[i];
            }
        } else { a0 = 0.f; a1 = 0.f; a2 = 0.f; a3 = 0.f; }
        {
            const float4* hp = hA + half*32;
#pragma unroll
            for (int j = 0; j < 32; ++j){
                float4 hv = hp[j];
                a0 += hv.x*w0[j]; a1 += hv.y*w0[j]; a2 += hv.z*w0[j]; a3 += hv.w*w0[j];
            }
        }
        // combine the two k-halves (lane s <-> s+32 hold same gate row)
        a0 += __shfl_xor(a0, 32); a1 += __shfl_xor(a1, 32);
        a2 += __shfl_xor(a2, 32); a3 += __shfl_xor(a3, 32);
        // activation split: half0 does rows 0,1; half1 rows 2,3
        if (!half){
            if (q == 2){ a0 = tanh_f(a0); a1 = tanh_f(a1); }
            else       { a0 = sig_f (a0); a1 = sig_f (a1); }
            gx[0][q][gu] = a0; gx[1][q][gu] = a1;
        } else {
            if (q == 2){ a2 = tanh_f(a2); a3 = tanh_f(a3); }
            else       { a2 = sig_f (a2); a3 = sig_f (a3); }
            gx[2][q][gu] = a2; gx[3][q][gu] = a3;
        }
        __syncthreads();   // B1: gates0 published

        if (q < 2){        // c0/h0 update, one owner per (row,unit)
            float gi = gx[ro][0][gu], gf = gx[ro][1][gu], gg = gx[ro][2][gu], go = gx[ro][3][gu];
            cOwn0 = gf*cOwn0 + gi*gg;
            ((float*)&hA[gu])[ro] = go * tanh_f(cOwn0);
        }
        __syncthreads();   // B2: new h0 published

        // ---------- layer 1: half0 = wih1 . hA_new, half1 = whh1 . hB ----------
        float d0, d1, d2, d3;
        if (!half){ d0 = b1; d1 = b1; d2 = b1; d3 = b1; }
        else      { d0 = 0.f; d1 = 0.f; d2 = 0.f; d3 = 0.f; }
        {
            const float4* hp = half ? hB : hA;
#pragma unroll
            for (int j = 0; j < 64; ++j){
                float4 hv = hp[j];
                d0 += hv.x*w1[j]; d1 += hv.y*w1[j]; d2 += hv.z*w1[j]; d3 += hv.w*w1[j];
            }
        }
        d0 += __shfl_xor(d0, 32); d1 += __shfl_xor(d1, 32);
        d2 += __shfl_xor(d2, 32); d3 += __shfl_xor(d3, 32);
        if (!half){
            if (q == 2){ d0 = tanh_f(d0); d1 = tanh_f(d1); }
            else       { d0 = sig_f (d0); d1 = sig_f (d1); }
            gx[0][q][gu] = d0; gx[1][q][gu] = d1;
        } else {
            if (q == 2){ d2 = tanh_f(d2); d3 = tanh_f(d3); }
            else       { d2 = sig_f (d2); d3 = sig_f (d3); }
            gx[2][q][gu] = d2; gx[3][q][gu] = d3;
        }
        __syncthreads();   // B3: gates1 published

        if (q < 2){
            float gi = gx[ro][0][gu], gf = gx[ro][1][gu], gg = gx[ro][2][gu], go = gx[ro][3][gu];
            cOwn1 = gf*cOwn1 + gi*gg;
            hOwn1 = go * tanh_f(cOwn1);
            ((float*)&hB[gu])[ro] = hOwn1;
        }
        __syncthreads();   // B4: h1 published; protects gx WAR across step boundary
    }

    // ---------- heads: wave 0 reads final h1 from LDS ----------
    if (tid < 64){
        const int u = tid;
        float4 hv = hB[u];
        float pm0 = hv.x*wmean[u], pm1 = hv.y*wmean[u], pm2 = hv.z*wmean[u], pm3 = hv.w*wmean[u];
        float pc0 = hv.x*wcrit[u], pc1 = hv.y*wcrit[u], pc2 = hv.z*wcrit[u], pc3 = hv.w*wcrit[u];
#pragma unroll
        for (int off = 32; off > 0; off >>= 1){
            pm0 += __shfl_down(pm0, off); pm1 += __shfl_down(pm1, off);
            pm2 += __shfl_down(pm2, off); pm3 += __shfl_down(pm3, off);
            pc0 += __shfl_down(pc0, off); pc1 += __shfl_down(pc1, off);
            pc2 += __shfl_down(pc2, off); pc3 += __shfl_down(pc3, off);
        }
        if (u == 0){
            float bm = bmean[0], bc = bcrit[0];
            float ml0 = pm0 + bm, ml1 = pm1 + bm, ml2 = pm2 + bm, ml3 = pm3 + bm;
            out[r0+0] = 2.0f*tanh_f(ml0); out[r0+1] = 2.0f*tanh_f(ml1);
            out[r0+2] = 2.0f*tanh_f(ml2); out[r0+3] = 2.0f*tanh_f(ml3);
            out[B_TOT+r0+0] = __logf(1.0f + __expf(ml0));
            out[B_TOT+r0+1] = __logf(1.0f + __expf(ml1));
            out[B_TOT+r0+2] = __logf(1.0f + __expf(ml2));
            out[B_TOT+r0+3] = __logf(1.0f + __expf(ml3));
            out[2*B_TOT+r0+0] = pc0 + bc; out[2*B_TOT+r0+1] = pc1 + bc;
            out[2*B_TOT+r0+2] = pc2 + bc; out[2*B_TOT+r0+3] = pc3 + bc;
        }
    }
}

extern "C" void kernel_launch(void* const* d_in, const int* in_sizes, int n_in,
                              void* d_out, int out_size, void* d_ws, size_t ws_size,
                              hipStream_t stream) {
    const float* x     = (const float*)d_in[0];
    const float* h0i   = (const float*)d_in[1];
    const float* c0i   = (const float*)d_in[2];
    const float* wih0  = (const float*)d_in[3];
    const float* whh0  = (const float*)d_in[4];
    const float* bih0  = (const float*)d_in[5];
    const float* bhh0  = (const float*)d_in[6];
    const float* wih1  = (const float*)d_in[7];
    const float* whh1  = (const float*)d_in[8];
    const float* bih1  = (const float*)d_in[9];
    const float* bhh1  = (const float*)d_in[10];
    const float* wmean = (const float*)d_in[11];
    const float* bmean = (const float*)d_in[12];
    const float* wcrit = (const float*)d_in[13];
    const float* bcrit = (const float*)d_in[14];

    lstm_ac_fused<<<NB, NT, 0, stream>>>(x, h0i, c0i, wih0, whh0, bih0, bhh0,
                                         wih1, whh1, bih1, bhh1,
                                         wmean, bmean, wcrit, bcrit,
                                         (float*)d_out);
}

// Round 4
// 1486.852 us; speedup vs baseline: 1.3776x; 1.2671x over previous
//
#include <hip/hip_runtime.h>
#include <math.h>

#define NB    512   // blocks, 2 batch rows each
#define NT    512   // threads (8 waves)
#define B_TOT 1024
#define T_TOT 512
#define XT    32    // x time-tile

__device__ __forceinline__ float rcp_f(float v){ return __builtin_amdgcn_rcpf(v); }
__device__ __forceinline__ float sig_f(float x){ return rcp_f(1.0f + __expf(-x)); }
__device__ __forceinline__ float tanh_f(float x){ return 1.0f - 2.0f*rcp_f(__expf(2.0f*x) + 1.0f); }

// quad-lane (bits[1:0]) butterfly sum via DPP quad_perm — VALU pipe, no LDS.
// ctrl must be an immediate -> template parameter.
template<int CTRL>
__device__ __forceinline__ float dpp_add(float v){
    int r = __builtin_amdgcn_update_dpp(0, __float_as_int(v), CTRL, 0xF, 0xF, false);
    return v + __int_as_float(r);
}
__device__ __forceinline__ float quad_sum(float v){
    v = dpp_add<0xB1>(v);   // quad_perm [1,0,3,2] : xor 1
    v = dpp_add<0x4E>(v);   // quad_perm [2,3,0,1] : xor 2
    return v;
}

__global__ __launch_bounds__(NT, 2) void lstm_ac_fused(
    const float* __restrict__ x,
    const float* __restrict__ h0i, const float* __restrict__ c0i,
    const float* __restrict__ wih0, const float* __restrict__ whh0,
    const float* __restrict__ bih0, const float* __restrict__ bhh0,
    const float* __restrict__ wih1, const float* __restrict__ whh1,
    const float* __restrict__ bih1, const float* __restrict__ bhh1,
    const float* __restrict__ wmean, const float* __restrict__ bmean,
    const float* __restrict__ wcrit, const float* __restrict__ bcrit,
    float* __restrict__ out)
{
    const int tid  = threadIdx.x;
    const int lane = tid & 63;
    const int wv   = tid >> 6;          // wave 0..7
    const int kq   = lane & 3;          // k-quarter
    const int ul   = (lane >> 2) & 7;   // unit-local
    const int gh   = lane >> 5;         // gate-half: 0 -> (i,f), 1 -> (g,o)
    const int unit = wv*8 + ul;         // hidden unit 0..63
    const int ga   = (2*gh)*64 + unit;  // gate row a (i or g)
    const int gb   = ga + 64;           // gate row b (f or o)
    const int r0   = blockIdx.x * 2;

    // h state: double-buffered, 4 bank-staggered copies (33 float4 = 528 B stride
    // -> copy c starts at bank 4c; kq group reads copy kq => disjoint banks)
    __shared__ float4 hA4[2][4][33];
    __shared__ float4 hB4[2][4][33];
    __shared__ float2 xt[5][XT+1];      // x tile (rows packed in float2); pad breaks i-dim bank overlap

    // ---- weights: 96 floats, static indices, pinned ----
    float w0a[16], w0b[16];             // whh0 rows ga/gb, k in [16kq,16kq+16)
    {
        const float* pa = whh0 + (size_t)ga*64 + kq*16;
        const float* pb = whh0 + (size_t)gb*64 + kq*16;
#pragma unroll
        for (int j = 0; j < 4; ++j){
            float4 v = ((const float4*)pa)[j];
            w0a[4*j]=v.x; w0a[4*j+1]=v.y; w0a[4*j+2]=v.z; w0a[4*j+3]=v.w;
            float4 u2 = ((const float4*)pb)[j];
            w0b[4*j]=u2.x; w0b[4*j+1]=u2.y; w0b[4*j+2]=u2.z; w0b[4*j+3]=u2.w;
        }
    }
    float w1a[32], w1b[32];             // kq<2: wih1 (on h0_new); kq>=2: whh1 (on h1_old)
    {
        const float* base1 = (kq < 2) ? wih1 : whh1;
        const float* qa = base1 + (size_t)ga*64 + (kq&1)*32;
        const float* qb = base1 + (size_t)gb*64 + (kq&1)*32;
#pragma unroll
        for (int j = 0; j < 8; ++j){
            float4 v = ((const float4*)qa)[j];
            w1a[4*j]=v.x; w1a[4*j+1]=v.y; w1a[4*j+2]=v.z; w1a[4*j+3]=v.w;
            float4 u2 = ((const float4*)qb)[j];
            w1b[4*j]=u2.x; w1b[4*j+1]=u2.y; w1b[4*j+2]=u2.z; w1b[4*j+3]=u2.w;
        }
    }
    // x-proj weights (i = kq; kq0 also i=4) and biases (kq0 only; others add 0)
    float xwa0 = wih0[ga*5 + kq], xwb0 = wih0[gb*5 + kq];
    float xwa1 = 0.f, xwb1 = 0.f, bb_a = 0.f, bb_b = 0.f, cb_a = 0.f, cb_b = 0.f;
    if (kq == 0){
        xwa1 = wih0[ga*5 + 4]; xwb1 = wih0[gb*5 + 4];
        bb_a = bih0[ga] + bhh0[ga]; bb_b = bih0[gb] + bhh0[gb];
        cb_a = bih1[ga] + bhh1[ga]; cb_b = bih1[gb] + bhh1[gb];
    }

    // pin weights into VGPRs (UNROLLED: static element -> no scratch; asm output
    // can't be rematerialized by reloading)
#pragma unroll
    for (int j = 0; j < 16; ++j) asm volatile("" : "+v"(w0a[j]), "+v"(w0b[j]));
#pragma unroll
    for (int j = 0; j < 32; ++j) asm volatile("" : "+v"(w1a[j]), "+v"(w1b[j]));

    // ---- cell state (redundant across the 8 (kq,gh) lanes of a unit) ----
    float c0r0 = c0i[(r0+0)*64 + unit];
    float c0r1 = c0i[(r0+1)*64 + unit];
    float c1r0 = c0i[(size_t)B_TOT*64 + (r0+0)*64 + unit];
    float c1r1 = c0i[(size_t)B_TOT*64 + (r0+1)*64 + unit];

    // ---- init h LDS (buffer 0, all 4 copies) ----
    if (tid < 64){
        int u = tid;
        float h0r0 = h0i[(r0+0)*64 + u], h0r1 = h0i[(r0+1)*64 + u];
        float h1r0 = h0i[(size_t)B_TOT*64 + (r0+0)*64 + u];
        float h1r1 = h0i[(size_t)B_TOT*64 + (r0+1)*64 + u];
#pragma unroll
        for (int c = 0; c < 4; ++c){
            float* dA = (float*)&hA4[0][c][u>>1] + (u&1)*2;
            dA[0] = h0r0; dA[1] = h0r1;
            float* dB = (float*)&hB4[0][c][u>>1] + (u&1)*2;
            dB[0] = h1r0; dB[1] = h1r1;
        }
    }

    // ---- per-lane LDS bases (linear reads w/ immediate offsets inside loop) ----
    const char* bL0 = (const char*)&hA4[0][kq][kq*8];
    const char* bL1 = (kq < 2) ? (const char*)&hA4[0][kq][(kq&1)*16]
                               : (const char*)&hB4[0][kq][(kq&1)*16];
    const bool  selL1 = (kq < 2);            // layer1 hA part reads buffer p^1
    char* bWA = (char*)&hA4[0][0][unit>>1] + (unit&1)*8;
    char* bWB = (char*)&hB4[0][0][unit>>1] + (unit&1)*8;
    const bool writer = (lane & 35) == 0;    // kq==0 && gh==0 : one writer per unit
    const int  BUFSZ = (int)sizeof(hA4[0]);  // 2112 B

    // activation constants: a-slot is tanh on gh1 (gate g), sigmoid otherwise
    const float kact = gh ? 2.f : 1.f;
    const float mact = gh ? 2.f : 1.f;
    const float cact = gh ? -1.f : 0.f;

    __syncthreads();

    const size_t xrow0 = (size_t)(r0+0)*T_TOT*5;
    const size_t xrow1 = (size_t)(r0+1)*T_TOT*5;

#pragma unroll 1
    for (int t = 0; t < T_TOT; ++t){
        const int p  = t & 1;
        const int tt = t & (XT-1);
        if (tt == 0){
            for (int e = tid; e < 2*XT*5; e += NT){
                int r  = e >= (XT*5);
                int e2 = e - r*(XT*5);
                int ts = e2 / 5, i = e2 - ts*5;
                ((float*)&xt[i][ts])[r] = x[(r ? xrow1 : xrow0) + (size_t)(t+ts)*5 + i];
            }
            __syncthreads();
        }

        const int offP  = p ? BUFSZ : 0;
        const int offP1 = offP ^ BUFSZ;

        // ================= layer 0 =================
        float sa0 = bb_a, sa1 = bb_a, sb0 = bb_b, sb1 = bb_b;
        {
            float2 xv = xt[kq][tt];
            sa0 += xv.x*xwa0; sa1 += xv.y*xwa0;
            sb0 += xv.x*xwb0; sb1 += xv.y*xwb0;
            float2 x4 = xt[4][tt];
            sa0 += x4.x*xwa1; sa1 += x4.y*xwa1;
            sb0 += x4.x*xwb1; sb1 += x4.y*xwb1;
        }
        {
            const float4* hp = (const float4*)(bL0 + offP);
#pragma unroll
            for (int j = 0; j < 8; ++j){
                float4 hv = hp[j];
                sa0 += hv.x*w0a[2*j];   sa1 += hv.y*w0a[2*j];
                sa0 += hv.z*w0a[2*j+1]; sa1 += hv.w*w0a[2*j+1];
                sb0 += hv.x*w0b[2*j];   sb1 += hv.y*w0b[2*j];
                sb0 += hv.z*w0b[2*j+1]; sb1 += hv.w*w0b[2*j+1];
            }
        }
        sa0 = quad_sum(sa0); sa1 = quad_sum(sa1);
        sb0 = quad_sum(sb0); sb1 = quad_sum(sb1);
        float aa0 = mact*sig_f(kact*sa0) + cact;
        float aa1 = mact*sig_f(kact*sa1) + cact;
        float ab0 = sig_f(sb0), ab1 = sig_f(sb1);
        float ra0 = __shfl_xor(aa0,32), ra1 = __shfl_xor(aa1,32);
        float rb0 = __shfl_xor(ab0,32), rb1 = __shfl_xor(ab1,32);
        float gi0 = gh? ra0:aa0, gg0 = gh? aa0:ra0, gf0 = gh? rb0:ab0, go0 = gh? ab0:rb0;
        float gi1 = gh? ra1:aa1, gg1 = gh? aa1:ra1, gf1 = gh? rb1:ab1, go1 = gh? ab1:rb1;
        c0r0 = gf0*c0r0 + gi0*gg0;
        c0r1 = gf1*c0r1 + gi1*gg1;
        float h00 = go0 * tanh_f(c0r0);
        float h01 = go1 * tanh_f(c0r1);
        if (writer){
            float2 hv; hv.x = h00; hv.y = h01;
            char* d = bWA + offP1;
#pragma unroll
            for (int c2 = 0; c2 < 4; ++c2) *(float2*)(d + c2*528) = hv;
        }
        __syncthreads();   // B1: h0_new published

        // ================= layer 1 =================
        float da0 = cb_a, da1 = cb_a, db0 = cb_b, db1 = cb_b;
        {
            const int offL1 = selL1 ? offP1 : offP;
            const float4* hp = (const float4*)(bL1 + offL1);
#pragma unroll
            for (int j = 0; j < 16; ++j){
                float4 hv = hp[j];
                da0 += hv.x*w1a[2*j];   da1 += hv.y*w1a[2*j];
                da0 += hv.z*w1a[2*j+1]; da1 += hv.w*w1a[2*j+1];
                db0 += hv.x*w1b[2*j];   db1 += hv.y*w1b[2*j];
                db0 += hv.z*w1b[2*j+1]; db1 += hv.w*w1b[2*j+1];
            }
        }
        da0 = quad_sum(da0); da1 = quad_sum(da1);
        db0 = quad_sum(db0); db1 = quad_sum(db1);
        float ea0 = mact*sig_f(kact*da0) + cact;
        float ea1 = mact*sig_f(kact*da1) + cact;
        float eb0 = sig_f(db0), eb1 = sig_f(db1);
        float ta0 = __shfl_xor(ea0,32), ta1 = __shfl_xor(ea1,32);
        float tb0 = __shfl_xor(eb0,32), tb1 = __shfl_xor(eb1,32);
        float hi0 = gh? ta0:ea0, hg0 = gh? ea0:ta0, hf0 = gh? tb0:eb0, ho0 = gh? eb0:tb0;
        float hi1 = gh? ta1:ea1, hg1 = gh? ea1:ta1, hf1 = gh? tb1:eb1, ho1 = gh? eb1:tb1;
        c1r0 = hf0*c1r0 + hi0*hg0;
        c1r1 = hf1*c1r1 + hi1*hg1;
        float h10 = ho0 * tanh_f(c1r0);
        float h11 = ho1 * tanh_f(c1r1);
        if (writer){
            float2 hv; hv.x = h10; hv.y = h11;
            char* d = bWB + offP1;
#pragma unroll
            for (int c2 = 0; c2 < 4; ++c2) *(float2*)(d + c2*528) = hv;
        }
        __syncthreads();   // B2: h1_new published (next step's inputs ready)
    }

    // ---- heads: final h1 is in hB4[0] (t=511 wrote buffer p^1 = 0) ----
    if (tid < 64){
        int u = tid;
        const float* s = (const float*)&hB4[0][0][u>>1] + (u&1)*2;
        float hr0 = s[0], hr1 = s[1];
        float pm0 = hr0*wmean[u], pm1 = hr1*wmean[u];
        float pc0 = hr0*wcrit[u], pc1 = hr1*wcrit[u];
#pragma unroll
        for (int o = 32; o > 0; o >>= 1){
            pm0 += __shfl_down(pm0,o); pm1 += __shfl_down(pm1,o);
            pc0 += __shfl_down(pc0,o); pc1 += __shfl_down(pc1,o);
        }
        if (u == 0){
            float bm = bmean[0], bc = bcrit[0];
            float m0 = pm0 + bm, m1 = pm1 + bm;
            out[r0+0]          = 2.f*tanh_f(m0);
            out[r0+1]          = 2.f*tanh_f(m1);
            out[B_TOT+r0+0]    = __logf(1.f + __expf(m0));
            out[B_TOT+r0+1]    = __logf(1.f + __expf(m1));
            out[2*B_TOT+r0+0]  = pc0 + bc;
            out[2*B_TOT+r0+1]  = pc1 + bc;
        }
    }
}

extern "C" void kernel_launch(void* const* d_in, const int* in_sizes, int n_in,
                              void* d_out, int out_size, void* d_ws, size_t ws_size,
                              hipStream_t stream) {
    const float* x     = (const float*)d_in[0];
    const float* h0i   = (const float*)d_in[1];
    const float* c0i   = (const float*)d_in[2];
    const float* wih0  = (const float*)d_in[3];
    const float* whh0  = (const float*)d_in[4];
    const float* bih0  = (const float*)d_in[5];
    const float* bhh0  = (const float*)d_in[6];
    const float* wih1  = (const float*)d_in[7];
    const float* whh1  = (const float*)d_in[8];
    const float* bih1  = (const float*)d_in[9];
    const float* bhh1  = (const float*)d_in[10];
    const float* wmean = (const float*)d_in[11];
    const float* bmean = (const float*)d_in[12];
    const float* wcrit = (const float*)d_in[13];
    const float* bcrit = (const float*)d_in[14];

    lstm_ac_fused<<<NB, NT, 0, stream>>>(x, h0i, c0i, wih0, whh0, bih0, bhh0,
                                         wih1, whh1, bih1, bhh1,
                                         wmean, bmean, wcrit, bcrit,
                                         (float*)d_out);
}

// Round 5
// 618.031 us; speedup vs baseline: 3.3142x; 2.4058x over previous
//
#include <hip/hip_runtime.h>
#include <math.h>

#define NB    512          // blocks, 2 batch rows each
#define NT    512          // 8 waves
#define ROWS  2
#define B_TOT 1024
#define T_TOT 512
#define XT    32           // x time-tile

typedef _Float16 f16;
typedef _Float16 f16x8 __attribute__((ext_vector_type(8)));
typedef float    f32x4 __attribute__((ext_vector_type(4)));

__device__ __forceinline__ float rcp_f(float v){ return __builtin_amdgcn_rcpf(v); }
__device__ __forceinline__ float sig_f(float x){ return rcp_f(1.0f + __expf(-x)); }
__device__ __forceinline__ float tanh_f(float x){ return 1.0f - 2.0f*rcp_f(__expf(2.0f*x) + 1.0f); }

#define MFMA16(a,b,c) __builtin_amdgcn_mfma_f32_16x16x32_f16((a),(b),(c),0,0,0)

__global__ __launch_bounds__(NT, 4) void lstm_mfma(
    const float* __restrict__ x,
    const float* __restrict__ h0i, const float* __restrict__ c0i,
    const float* __restrict__ wih0, const float* __restrict__ whh0,
    const float* __restrict__ bih0, const float* __restrict__ bhh0,
    const float* __restrict__ wih1, const float* __restrict__ whh1,
    const float* __restrict__ bih1, const float* __restrict__ bhh1,
    const float* __restrict__ wmean, const float* __restrict__ bmean,
    const float* __restrict__ wcrit, const float* __restrict__ bcrit,
    float* __restrict__ out)
{
    const int tid  = threadIdx.x;
    const int lane = tid & 63;
    const int wv   = tid >> 6;        // wave 0..7
    const int ug   = wv & 3;          // unit-group: units [16ug, 16ug+16)
    const int gp   = wv >> 2;         // gate pair: 0 -> gates {0,1}, 1 -> {2,3}
    const int mrow = lane & 15;       // M-row in tile (gate unit) / N-col (batch)
    const int kgrp = lane >> 4;       // 0..3
    const int r0   = blockIdx.x * ROWS;

    // h as f16 [16 rows][64 units + 8 pad]: stride 144 B (16-B aligned, 2-way banks)
    __shared__ __align__(16) f16  hA[16][72];
    __shared__ __align__(16) f16  hB[16][72];
    __shared__ __align__(16) float part[4][ROWS][64];  // gate partials [gate][row][unit]
    __shared__ float xt[ROWS][XT][8];                  // x tile (i<5 used)

    // ---- weight A-fragments (f16, loaded once; 48 VGPRs) ----
    // A layout: row = mrow, k = 32*chunk + kgrp*8 + j (contiguous 8)
    f16x8 a0[2][2];   // layer0: [gate-slot][k-chunk] of whh0
    f16x8 a1[2][4];   // layer1: chunks 0,1 = wih1 (on h0_new), 2,3 = whh1 (on h1_old)
#pragma unroll
    for (int s = 0; s < 2; ++s){
        const int q  = gp*2 + s;
        const int gr = q*64 + ug*16 + mrow;
#pragma unroll
        for (int c = 0; c < 2; ++c){
            const float* p = whh0 + (size_t)gr*64 + c*32 + kgrp*8;
            f16x8 v;
#pragma unroll
            for (int j = 0; j < 8; ++j) v[j] = (f16)p[j];
            a0[s][c] = v;
        }
#pragma unroll
        for (int c = 0; c < 4; ++c){
            const float* base = (c < 2) ? wih1 : whh1;
            const float* p = base + (size_t)gr*64 + (c&1)*32 + kgrp*8;
            f16x8 v;
#pragma unroll
            for (int j = 0; j < 8; ++j) v[j] = (f16)p[j];
            a1[s][c] = v;
        }
    }

    // ---- cell workers: 128 threads, wave-aligned; SIMD-balanced by block parity ----
    const int  woff = (blockIdx.x & 1) ? 128 : 0;  // waves {0,1} or {2,3}
    const int  wjob = tid - woff;
    const bool isW  = (wjob >= 0) && (wjob < 128);
    const int  uu   = wjob & 63;      // unit   (valid if isW)
    const int  rr   = (wjob >> 6) & 1;// row
    float xw[20], b0g[4], b1g[4];
    float c0own = 0.f, c1own = 0.f, h1own = 0.f;
    if (isW){
#pragma unroll
        for (int q2 = 0; q2 < 4; ++q2){
#pragma unroll
            for (int i = 0; i < 5; ++i) xw[q2*5+i] = wih0[(q2*64+uu)*5 + i];
            b0g[q2] = bih0[q2*64+uu] + bhh0[q2*64+uu];
            b1g[q2] = bih1[q2*64+uu] + bhh1[q2*64+uu];
        }
        c0own = c0i[(r0+rr)*64 + uu];
        c1own = c0i[(size_t)B_TOT*64 + (r0+rr)*64 + uu];
    }

    // ---- init LDS: zero (pad rows/cols), then real h0 rows ----
    for (int e = tid; e < 16*72; e += NT){
        ((f16*)hA)[e] = (f16)0.f; ((f16*)hB)[e] = (f16)0.f;
    }
    __syncthreads();
    if (tid < ROWS*64){
        int u = tid & 63, r = tid >> 6;
        hA[r][u] = (f16)h0i[(r0+r)*64 + u];
        hB[r][u] = (f16)h0i[(size_t)B_TOT*64 + (r0+r)*64 + u];
    }
    __syncthreads();

#pragma unroll 1
    for (int t = 0; t < T_TOT; ++t){
        const int tt = t & (XT-1);
        if (tt == 0){
            for (int e = tid; e < ROWS*XT*5; e += NT){
                int r = e/(XT*5), rem = e - r*(XT*5), ts = rem/5, i = rem - ts*5;
                xt[r][ts][i] = x[((size_t)(r0+r)*T_TOT + (t+ts))*5 + i];
            }
        }

        // ===== Phase A: layer-0 MFMA (gates = whh0 . h0_prev) =====
        {
            f16x8 bf0 = *(const f16x8*)&hA[mrow][kgrp*8];
            f16x8 bf1 = *(const f16x8*)&hA[mrow][32 + kgrp*8];
            f32x4 ac0 = {0.f,0.f,0.f,0.f}, ac1 = {0.f,0.f,0.f,0.f};
            ac0 = MFMA16(a0[0][0], bf0, ac0);
            ac0 = MFMA16(a0[0][1], bf1, ac0);
            ac1 = MFMA16(a0[1][0], bf0, ac1);
            ac1 = MFMA16(a0[1][1], bf1, ac1);
            if (mrow < ROWS){
                *(f32x4*)&part[gp*2+0][mrow][ug*16 + kgrp*4] = ac0;
                *(f32x4*)&part[gp*2+1][mrow][ug*16 + kgrp*4] = ac1;
            }
        }
        __syncthreads();   // A: partials ready; xt staged

        // ===== Phase B: layer-0 cell update (fp32) =====
        if (isW){
            float xv0 = xt[rr][tt][0], xv1 = xt[rr][tt][1], xv2 = xt[rr][tt][2],
                  xv3 = xt[rr][tt][3], xv4 = xt[rr][tt][4];
            float pre[4];
#pragma unroll
            for (int q2 = 0; q2 < 4; ++q2){
                float p_ = part[q2][rr][uu] + b0g[q2];
                p_ += xw[q2*5+0]*xv0 + xw[q2*5+1]*xv1 + xw[q2*5+2]*xv2
                    + xw[q2*5+3]*xv3 + xw[q2*5+4]*xv4;
                pre[q2] = p_;
            }
            float ig = sig_f(pre[0]), fg = sig_f(pre[1]);
            float gg = tanh_f(pre[2]), og = sig_f(pre[3]);
            c0own = fg*c0own + ig*gg;
            float h0n = og * tanh_f(c0own);
            hA[rr][uu] = (f16)h0n;
        }
        __syncthreads();   // B: h0_new published

        // ===== Phase C: layer-1 MFMA (wih1 . h0_new + whh1 . h1_old) =====
        {
            f16x8 bc0 = *(const f16x8*)&hA[mrow][kgrp*8];
            f16x8 bc1 = *(const f16x8*)&hA[mrow][32 + kgrp*8];
            f16x8 bc2 = *(const f16x8*)&hB[mrow][kgrp*8];
            f16x8 bc3 = *(const f16x8*)&hB[mrow][32 + kgrp*8];
            f32x4 dc0 = {0.f,0.f,0.f,0.f}, dc1 = {0.f,0.f,0.f,0.f};
            dc0 = MFMA16(a1[0][0], bc0, dc0);
            dc0 = MFMA16(a1[0][1], bc1, dc0);
            dc0 = MFMA16(a1[0][2], bc2, dc0);
            dc0 = MFMA16(a1[0][3], bc3, dc0);
            dc1 = MFMA16(a1[1][0], bc0, dc1);
            dc1 = MFMA16(a1[1][1], bc1, dc1);
            dc1 = MFMA16(a1[1][2], bc2, dc1);
            dc1 = MFMA16(a1[1][3], bc3, dc1);
            if (mrow < ROWS){
                *(f32x4*)&part[gp*2+0][mrow][ug*16 + kgrp*4] = dc0;
                *(f32x4*)&part[gp*2+1][mrow][ug*16 + kgrp*4] = dc1;
            }
        }
        __syncthreads();   // C: layer-1 partials ready

        // ===== Phase D: layer-1 cell update =====
        if (isW){
            float pre[4];
#pragma unroll
            for (int q2 = 0; q2 < 4; ++q2) pre[q2] = part[q2][rr][uu] + b1g[q2];
            float ig = sig_f(pre[0]), fg = sig_f(pre[1]);
            float gg = tanh_f(pre[2]), og = sig_f(pre[3]);
            c1own = fg*c1own + ig*gg;
            h1own = og * tanh_f(c1own);
            hB[rr][uu] = (f16)h1own;
        }
        __syncthreads();   // D: h1_new published
    }

    // ===== heads: worker waves hold h1own (fp32), lane == unit =====
    if (isW){
        float pm = h1own * wmean[uu];
        float pc = h1own * wcrit[uu];
#pragma unroll
        for (int o = 32; o > 0; o >>= 1){
            pm += __shfl_down(pm, o);
            pc += __shfl_down(pc, o);
        }
        if (uu == 0){
            float m = pm + bmean[0];
            out[r0+rr]           = 2.f*tanh_f(m);
            out[B_TOT + r0+rr]   = __logf(1.f + __expf(m));
            out[2*B_TOT + r0+rr] = pc + bcrit[0];
        }
    }
}

extern "C" void kernel_launch(void* const* d_in, const int* in_sizes, int n_in,
                              void* d_out, int out_size, void* d_ws, size_t ws_size,
                              hipStream_t stream) {
    const float* x     = (const float*)d_in[0];
    const float* h0i   = (const float*)d_in[1];
    const float* c0i   = (const float*)d_in[2];
    const float* wih0  = (const float*)d_in[3];
    const float* whh0  = (const float*)d_in[4];
    const float* bih0  = (const float*)d_in[5];
    const float* bhh0  = (const float*)d_in[6];
    const float* wih1  = (const float*)d_in[7];
    const float* whh1  = (const float*)d_in[8];
    const float* bih1  = (const float*)d_in[9];
    const float* bhh1  = (const float*)d_in[10];
    const float* wmean = (const float*)d_in[11];
    const float* bmean = (const float*)d_in[12];
    const float* wcrit = (const float*)d_in[13];
    const float* bcrit = (const float*)d_in[14];

    lstm_mfma<<<NB, NT, 0, stream>>>(x, h0i, c0i, wih0, whh0, bih0, bhh0,
                                     wih1, whh1, bih1, bhh1,
                                     wmean, bmean, wcrit, bcrit,
                                     (float*)d_out);
}

// Round 6
// 471.876 us; speedup vs baseline: 4.3407x; 1.3097x over previous
//
#include <hip/hip_runtime.h>
#include <math.h>

#define NB    256   // blocks = CU count; 4 batch rows each
#define NT    512   // 8 waves: 0-3 = layer0 (X), 4-7 = layer1 (Y)
#define ROWS  4
#define B_TOT 1024
#define T_TOT 512
#define HROW  104   // f16 per h-row (208 B: 16B-aligned, bank-friendly)
#define XT    32

typedef _Float16 f16;
typedef _Float16 f16x8 __attribute__((ext_vector_type(8)));
typedef _Float16 f16x4 __attribute__((ext_vector_type(4)));
typedef float    f32x4 __attribute__((ext_vector_type(4)));

__device__ __forceinline__ float rcp_f(float v){ return __builtin_amdgcn_rcpf(v); }
__device__ __forceinline__ float sig_f(float x){ return rcp_f(1.0f + __expf(-x)); }
__device__ __forceinline__ float tanh_f(float x){ return 1.0f - 2.0f*rcp_f(__expf(2.0f*x) + 1.0f); }

#define MFMA16(a,b,c) __builtin_amdgcn_mfma_f32_16x16x32_f16((a),(b),(c),0,0,0)

__global__ __launch_bounds__(NT, 2) void lstm_pipe(
    const float* __restrict__ x,
    const float* __restrict__ h0i, const float* __restrict__ c0i,
    const float* __restrict__ wih0, const float* __restrict__ whh0,
    const float* __restrict__ bih0, const float* __restrict__ bhh0,
    const float* __restrict__ wih1, const float* __restrict__ whh1,
    const float* __restrict__ bih1, const float* __restrict__ bhh1,
    const float* __restrict__ wmean, const float* __restrict__ bmean,
    const float* __restrict__ wcrit, const float* __restrict__ bcrit,
    float* __restrict__ out)
{
    const int tid  = threadIdx.x;
    const int lane = tid & 63;
    const int wv   = tid >> 6;
    const bool isX = (wv < 4);        // layer-0 waves
    const int ug   = wv & 3;          // unit-group: units [16ug,16ug+16)
    const int l15  = lane & 15;       // A-row m / B-col n / D-col (batch)
    const int kgrp = lane >> 4;       // k-group; D rows = kgrp*4+r
    const int r0   = blockIdx.x * ROWS;

    // h0 buffer rows: k0..63 = h0, k64..68 = x[t], k69..103 = 0
    __shared__ __align__(16) f16 hbuf[2][16][HROW];
    // h1 buffer rows: k0..63 = h1, rest 0
    __shared__ __align__(16) f16 ybuf[2][16][HROW];
    __shared__ float xt[ROWS][XT][5];

    // ---------- per-wave constant fragments ----------
    f16x8 aX[4][3];  float bX[4][4];  float cX[4];   // X: whh0 + x-chunk, bias0, c0
    f16x8 aY[4][4];  float bY[4][4];  float cY[4];   // Y: wih1|whh1, bias1, c1

    if (isX){
#pragma unroll
        for (int q = 0; q < 4; ++q){
            const int gr = q*64 + ug*16 + l15;
#pragma unroll
            for (int c2 = 0; c2 < 2; ++c2){
                const float* pw = whh0 + (size_t)gr*64 + c2*32 + kgrp*8;
                f16x8 v;
#pragma unroll
                for (int j = 0; j < 8; ++j) v[j] = (f16)pw[j];
                aX[q][c2] = v;
            }
            {   // chunk 2: k-local = kgrp*8+j maps to global k 64..95 (x rows 0..4, rest 0)
                f16x8 v;
#pragma unroll
                for (int j = 0; j < 8; ++j){
                    int k = kgrp*8 + j;
                    v[j] = (k < 5) ? (f16)wih0[gr*5 + k] : (f16)0.f;
                }
                aX[q][2] = v;
            }
#pragma unroll
            for (int r = 0; r < 4; ++r){
                int gu = q*64 + ug*16 + kgrp*4 + r;
                bX[q][r] = bih0[gu] + bhh0[gu];
            }
        }
#pragma unroll
        for (int r = 0; r < 4; ++r){
            int un = ug*16 + kgrp*4 + r;
            cX[r] = (l15 < ROWS) ? c0i[(size_t)(r0+l15)*64 + un] : 0.f;
        }
    } else {
#pragma unroll
        for (int q = 0; q < 4; ++q){
            const int gr = q*64 + ug*16 + l15;
#pragma unroll
            for (int c2 = 0; c2 < 2; ++c2){
                const float* pw = wih1 + (size_t)gr*64 + c2*32 + kgrp*8;
                const float* qw = whh1 + (size_t)gr*64 + c2*32 + kgrp*8;
                f16x8 v, u2;
#pragma unroll
                for (int j = 0; j < 8; ++j){ v[j] = (f16)pw[j]; u2[j] = (f16)qw[j]; }
                aY[q][c2]   = v;
                aY[q][2+c2] = u2;
            }
#pragma unroll
            for (int r = 0; r < 4; ++r){
                int gu = q*64 + ug*16 + kgrp*4 + r;
                bY[q][r] = bih1[gu] + bhh1[gu];
            }
        }
#pragma unroll
        for (int r = 0; r < 4; ++r){
            int un = ug*16 + kgrp*4 + r;
            cY[r] = (l15 < ROWS) ? c0i[(size_t)B_TOT*64 + (size_t)(r0+l15)*64 + un] : 0.f;
        }
    }

    // ---------- LDS init ----------
    for (int e = tid; e < 2*16*HROW; e += NT){
        ((f16*)hbuf)[e] = (f16)0.f;
        ((f16*)ybuf)[e] = (f16)0.f;
    }
    __syncthreads();
    if (tid < ROWS*64){
        int cc = tid >> 6, u = tid & 63;
        hbuf[0][cc][u] = (f16)h0i[(size_t)(r0+cc)*64 + u];
        ybuf[1][cc][u] = (f16)h0i[(size_t)B_TOT*64 + (size_t)(r0+cc)*64 + u];
    }
    if (tid < ROWS*5){
        int cc = tid/5, i = tid - cc*5;
        hbuf[0][cc][64+i] = (f16)x[(size_t)(r0+cc)*T_TOT*5 + i];  // x[0]
    }
    for (int e = tid; e < ROWS*XT*5; e += NT){
        int r = e/160, rem = e - r*160, ts = rem/5, i = rem - ts*5;
        xt[r][ts][i] = x[((size_t)(r0+r)*T_TOT + ts)*5 + i];      // tile 0
    }
    __syncthreads();

    // ---------- 513 pipelined ticks: X does layer0 step t, Y does layer1 step t-1 ----------
#pragma unroll 1
    for (int t = 0; t <= T_TOT; ++t){
        const int p = t & 1;

        if ((t+1) < T_TOT && ((t+1) & 31) == 0){      // stage next x tile
            for (int e = tid; e < ROWS*XT*5; e += NT){
                int r = e/160, rem = e - r*160, ts = rem/5, i = rem - ts*5;
                xt[r][ts][i] = x[((size_t)(r0+r)*T_TOT + (t+1+ts))*5 + i];
            }
            __syncthreads();
        }
        if ((t+1) < T_TOT && tid < ROWS*5){           // copy x[t+1] -> write buffer
            int cc = tid/5, i = tid - cc*5;
            hbuf[p^1][cc][64+i] = (f16)xt[cc][(t+1)&31][i];
        }

        if (isX){ if (t < T_TOT){
            const f16* bp = &hbuf[p][l15][kgrp*8];
            f16x8 b0 = *(const f16x8*)(bp);
            f16x8 b1 = *(const f16x8*)(bp + 32);
            f16x8 b2 = *(const f16x8*)(bp + 64);
            f32x4 ac[4];
#pragma unroll
            for (int q = 0; q < 4; ++q){
                f32x4 a = {bX[q][0], bX[q][1], bX[q][2], bX[q][3]};
                a = MFMA16(aX[q][0], b0, a);
                a = MFMA16(aX[q][1], b1, a);
                a = MFMA16(aX[q][2], b2, a);
                ac[q] = a;
            }
            f16x4 hv;
#pragma unroll
            for (int r = 0; r < 4; ++r){
                float ii = ac[0][r], ff = ac[1][r], gg = ac[2][r], oo = ac[3][r];
                cX[r] = sig_f(ff)*cX[r] + sig_f(ii)*tanh_f(gg);
                hv[r] = (f16)(sig_f(oo)*tanh_f(cX[r]));
            }
            *(f16x4*)&hbuf[p^1][l15][ug*16 + kgrp*4] = hv;
        }} else { if (t >= 1){
            const f16* hp = &hbuf[p][l15][kgrp*8];
            f16x8 b0 = *(const f16x8*)(hp);
            f16x8 b1 = *(const f16x8*)(hp + 32);
            const f16* yp = &ybuf[p][l15][kgrp*8];
            f16x8 b2 = *(const f16x8*)(yp);
            f16x8 b3 = *(const f16x8*)(yp + 32);
            f32x4 ac[4];
#pragma unroll
            for (int q = 0; q < 4; ++q){
                f32x4 a = {bY[q][0], bY[q][1], bY[q][2], bY[q][3]};
                a = MFMA16(aY[q][0], b0, a);
                a = MFMA16(aY[q][1], b1, a);
                a = MFMA16(aY[q][2], b2, a);
                a = MFMA16(aY[q][3], b3, a);
                ac[q] = a;
            }
            f16x4 hv;
#pragma unroll
            for (int r = 0; r < 4; ++r){
                float ii = ac[0][r], ff = ac[1][r], gg = ac[2][r], oo = ac[3][r];
                cY[r] = sig_f(ff)*cY[r] + sig_f(ii)*tanh_f(gg);
                hv[r] = (f16)(sig_f(oo)*tanh_f(cY[r]));
            }
            *(f16x4*)&ybuf[p^1][l15][ug*16 + kgrp*4] = hv;
        }}
        __syncthreads();
    }

    // ---------- heads: final h1 = ybuf[1] (written at tick 512) ----------
    if (wv < ROWS){
        const int cc = wv, u = lane;
        float hr = (float)ybuf[1][cc][u];
        float pm = hr * wmean[u];
        float pc = hr * wcrit[u];
#pragma unroll
        for (int o = 32; o > 0; o >>= 1){
            pm += __shfl_down(pm, o);
            pc += __shfl_down(pc, o);
        }
        if (u == 0){
            float m = pm + bmean[0];
            out[r0+cc]           = 2.f*tanh_f(m);
            out[B_TOT + r0+cc]   = __logf(1.f + __expf(m));
            out[2*B_TOT + r0+cc] = pc + bcrit[0];
        }
    }
}

extern "C" void kernel_launch(void* const* d_in, const int* in_sizes, int n_in,
                              void* d_out, int out_size, void* d_ws, size_t ws_size,
                              hipStream_t stream) {
    const float* x     = (const float*)d_in[0];
    const float* h0i   = (const float*)d_in[1];
    const float* c0i   = (const float*)d_in[2];
    const float* wih0  = (const float*)d_in[3];
    const float* whh0  = (const float*)d_in[4];
    const float* bih0  = (const float*)d_in[5];
    const float* bhh0  = (const float*)d_in[6];
    const float* wih1  = (const float*)d_in[7];
    const float* whh1  = (const float*)d_in[8];
    const float* bih1  = (const float*)d_in[9];
    const float* bhh1  = (const float*)d_in[10];
    const float* wmean = (const float*)d_in[11];
    const float* bmean = (const float*)d_in[12];
    const float* wcrit = (const float*)d_in[13];
    const float* bcrit = (const float*)d_in[14];

    lstm_pipe<<<NB, NT, 0, stream>>>(x, h0i, c0i, wih0, whh0, bih0, bhh0,
                                     wih1, whh1, bih1, bhh1,
                                     wmean, bmean, wcrit, bcrit,
                                     (float*)d_out);
}

// Round 7
// 350.511 us; speedup vs baseline: 5.8437x; 1.3463x over previous
//
#include <hip/hip_runtime.h>
#include <math.h>

#define NB    256   // blocks = CU count; 4 batch rows each
#define NT    512   // 8 waves: 0-3 = layer0 (X), 4-7 = layer1 (Y)
#define ROWS  4
#define B_TOT 1024
#define T_TOT 512
#define HROW  104   // f16 per h-row (208 B; 16B-aligned; conflict-free b128 pattern)
#define XT    32

typedef _Float16 f16;
typedef _Float16 f16x8 __attribute__((ext_vector_type(8)));
typedef float    f32x4 __attribute__((ext_vector_type(4)));

__device__ __forceinline__ float rcp_f(float v){ return __builtin_amdgcn_rcpf(v); }
__device__ __forceinline__ float sig_f(float x){ return rcp_f(1.0f + __expf(-x)); }
__device__ __forceinline__ float tanh_f(float x){ return 1.0f - 2.0f*rcp_f(__expf(2.0f*x) + 1.0f); }

#define MFMA16(a,b,c) __builtin_amdgcn_mfma_f32_16x16x32_f16((a),(b),(c),0,0,0)

__global__ __launch_bounds__(NT, 2) void lstm_pipe(
    const float* __restrict__ x,
    const float* __restrict__ h0i, const float* __restrict__ c0i,
    const float* __restrict__ wih0, const float* __restrict__ whh0,
    const float* __restrict__ bih0, const float* __restrict__ bhh0,
    const float* __restrict__ wih1, const float* __restrict__ whh1,
    const float* __restrict__ bih1, const float* __restrict__ bhh1,
    const float* __restrict__ wmean, const float* __restrict__ bmean,
    const float* __restrict__ wcrit, const float* __restrict__ bcrit,
    float* __restrict__ out)
{
    const int tid  = threadIdx.x;
    const int lane = tid & 63;
    const int wv   = tid >> 6;
    const bool isX = (wv < 4);        // layer-0 waves
    const int ug   = wv & 3;          // unit-group: units [16ug,16ug+16)
    const int l15  = lane & 15;       // A-row m / B-col n (batch)
    const int kgrp = lane >> 4;       // k-group
    const int r0   = blockIdx.x * ROWS;
    // packed cell-update ownership: one (unit,batch) slot per lane
    const int uloc = lane >> 2;       // unit-local 0..15
    const int bb   = lane & 3;        // batch row 0..3

    // h0 rows: k0..63 = h0, k64..68 = x[t], k69..103 = 0
    __shared__ __align__(16) f16 hbuf[2][16][HROW];
    // h1 rows: k0..63 = h1, rest 0
    __shared__ __align__(16) f16 ybuf[2][16][HROW];
    __shared__ float xt[ROWS][XT][5];
    // wave-private gate bounce buffer: [wave][gate][batch][unit-local]
    __shared__ __align__(16) float gbuf[8][4][4][16];

    // ---------- per-wave constant fragments ----------
    f16x8 aX[4][3];   // X: whh0 chunks 0,1 + (x|0) chunk 2
    f16x8 aY[4][4];   // Y: wih1 chunks 0,1 ; whh1 chunks 2,3
    float bpk[4];     // bias for this lane's owned unit, per gate
    float cOwn;       // owned cell state

    if (isX){
#pragma unroll
        for (int q = 0; q < 4; ++q){
            const int gr = q*64 + ug*16 + l15;
#pragma unroll
            for (int c2 = 0; c2 < 2; ++c2){
                const float* pw = whh0 + (size_t)gr*64 + c2*32 + kgrp*8;
                f16x8 v;
#pragma unroll
                for (int j = 0; j < 8; ++j) v[j] = (f16)pw[j];
                aX[q][c2] = v;
            }
            {   // chunk 2: global k 64..95 -> x rows 64..68, rest 0
                f16x8 v;
#pragma unroll
                for (int j = 0; j < 8; ++j){
                    int k = kgrp*8 + j;
                    v[j] = (k < 5) ? (f16)wih0[gr*5 + k] : (f16)0.f;
                }
                aX[q][2] = v;
            }
            const int gu = q*64 + ug*16 + uloc;
            bpk[q] = bih0[gu] + bhh0[gu];
        }
        cOwn = c0i[(size_t)(r0+bb)*64 + ug*16 + uloc];
    } else {
#pragma unroll
        for (int q = 0; q < 4; ++q){
            const int gr = q*64 + ug*16 + l15;
#pragma unroll
            for (int c2 = 0; c2 < 2; ++c2){
                const float* pw = wih1 + (size_t)gr*64 + c2*32 + kgrp*8;
                const float* qw = whh1 + (size_t)gr*64 + c2*32 + kgrp*8;
                f16x8 v, u2;
#pragma unroll
                for (int j = 0; j < 8; ++j){ v[j] = (f16)pw[j]; u2[j] = (f16)qw[j]; }
                aY[q][c2]   = v;
                aY[q][2+c2] = u2;
            }
            const int gu = q*64 + ug*16 + uloc;
            bpk[q] = bih1[gu] + bhh1[gu];
        }
        cOwn = c0i[(size_t)B_TOT*64 + (size_t)(r0+bb)*64 + ug*16 + uloc];
    }

    // ---------- LDS init ----------
    for (int e = tid; e < 2*16*HROW; e += NT){
        ((f16*)hbuf)[e] = (f16)0.f;
        ((f16*)ybuf)[e] = (f16)0.f;
    }
    __syncthreads();
    if (tid < ROWS*64){
        int cc = tid >> 6, u = tid & 63;
        hbuf[0][cc][u] = (f16)h0i[(size_t)(r0+cc)*64 + u];
        ybuf[1][cc][u] = (f16)h0i[(size_t)B_TOT*64 + (size_t)(r0+cc)*64 + u];
    }
    if (tid < ROWS*5){
        int cc = tid/5, i = tid - cc*5;
        hbuf[0][cc][64+i] = (f16)x[(size_t)(r0+cc)*T_TOT*5 + i];  // x[0]
    }
    for (int e = tid; e < ROWS*XT*5; e += NT){
        int r = e/160, rem = e - r*160, ts = rem/5, i = rem - ts*5;
        xt[r][ts][i] = x[((size_t)(r0+r)*T_TOT + ts)*5 + i];      // tile 0
    }
    __syncthreads();

    // ---------- 513 pipelined ticks: X = layer0 step t, Y = layer1 step t-1 ----------
#pragma unroll 1
    for (int t = 0; t <= T_TOT; ++t){
        const int p = t & 1;

        if ((t+1) < T_TOT && ((t+1) & 31) == 0){      // stage next x tile
            for (int e = tid; e < ROWS*XT*5; e += NT){
                int r = e/160, rem = e - r*160, ts = rem/5, i = rem - ts*5;
                xt[r][ts][i] = x[((size_t)(r0+r)*T_TOT + (t+1+ts))*5 + i];
            }
            __syncthreads();
        }
        if ((t+1) < T_TOT && tid < ROWS*5){           // x[t+1] -> write buffer
            int cc = tid/5, i = tid - cc*5;
            hbuf[p^1][cc][64+i] = (f16)xt[cc][(t+1)&31][i];
        }

        if (isX){ if (t < T_TOT){
            const f16* bp = &hbuf[p][l15][kgrp*8];
            f16x8 b0 = *(const f16x8*)(bp);
            f16x8 b1 = *(const f16x8*)(bp + 32);
            f16x8 b2 = *(const f16x8*)(bp + 64);
#pragma unroll
            for (int q = 0; q < 4; ++q){
                f32x4 a = {0.f,0.f,0.f,0.f};
                a = MFMA16(aX[q][0], b0, a);
                a = MFMA16(aX[q][1], b1, a);
                a = MFMA16(aX[q][2], b2, a);
                if (l15 < ROWS) *(f32x4*)&gbuf[wv][q][l15][kgrp*4] = a;
            }
            // packed cell update: one (unit,batch) per lane
            float ii = gbuf[wv][0][bb][uloc] + bpk[0];
            float ff = gbuf[wv][1][bb][uloc] + bpk[1];
            float gg = gbuf[wv][2][bb][uloc] + bpk[2];
            float oo = gbuf[wv][3][bb][uloc] + bpk[3];
            cOwn = sig_f(ff)*cOwn + sig_f(ii)*tanh_f(gg);
            hbuf[p^1][bb][ug*16 + uloc] = (f16)(sig_f(oo)*tanh_f(cOwn));
        }} else { if (t >= 1){
            const f16* hp = &hbuf[p][l15][kgrp*8];
            f16x8 b0 = *(const f16x8*)(hp);
            f16x8 b1 = *(const f16x8*)(hp + 32);
            const f16* yp = &ybuf[p][l15][kgrp*8];
            f16x8 b2 = *(const f16x8*)(yp);
            f16x8 b3 = *(const f16x8*)(yp + 32);
#pragma unroll
            for (int q = 0; q < 4; ++q){
                f32x4 a = {0.f,0.f,0.f,0.f};
                a = MFMA16(aY[q][0], b0, a);
                a = MFMA16(aY[q][1], b1, a);
                a = MFMA16(aY[q][2], b2, a);
                a = MFMA16(aY[q][3], b3, a);
                if (l15 < ROWS) *(f32x4*)&gbuf[wv][q][l15][kgrp*4] = a;
            }
            float ii = gbuf[wv][0][bb][uloc] + bpk[0];
            float ff = gbuf[wv][1][bb][uloc] + bpk[1];
            float gg = gbuf[wv][2][bb][uloc] + bpk[2];
            float oo = gbuf[wv][3][bb][uloc] + bpk[3];
            cOwn = sig_f(ff)*cOwn + sig_f(ii)*tanh_f(gg);
            ybuf[p^1][bb][ug*16 + uloc] = (f16)(sig_f(oo)*tanh_f(cOwn));
        }}
        __syncthreads();
    }

    // ---------- heads: final h1 = ybuf[1] (written at tick 512) ----------
    if (wv < ROWS){
        const int cc = wv, u = lane;
        float hr = (float)ybuf[1][cc][u];
        float pm = hr * wmean[u];
        float pc = hr * wcrit[u];
#pragma unroll
        for (int o = 32; o > 0; o >>= 1){
            pm += __shfl_down(pm, o);
            pc += __shfl_down(pc, o);
        }
        if (u == 0){
            float m = pm + bmean[0];
            out[r0+cc]           = 2.f*tanh_f(m);
            out[B_TOT + r0+cc]   = __logf(1.f + __expf(m));
            out[2*B_TOT + r0+cc] = pc + bcrit[0];
        }
    }
}

extern "C" void kernel_launch(void* const* d_in, const int* in_sizes, int n_in,
                              void* d_out, int out_size, void* d_ws, size_t ws_size,
                              hipStream_t stream) {
    const float* x     = (const float*)d_in[0];
    const float* h0i   = (const float*)d_in[1];
    const float* c0i   = (const float*)d_in[2];
    const float* wih0  = (const float*)d_in[3];
    const float* whh0  = (const float*)d_in[4];
    const float* bih0  = (const float*)d_in[5];
    const float* bhh0  = (const float*)d_in[6];
    const float* wih1  = (const float*)d_in[7];
    const float* whh1  = (const float*)d_in[8];
    const float* bih1  = (const float*)d_in[9];
    const float* bhh1  = (const float*)d_in[10];
    const float* wmean = (const float*)d_in[11];
    const float* bmean = (const float*)d_in[12];
    const float* wcrit = (const float*)d_in[13];
    const float* bcrit = (const float*)d_in[14];

    lstm_pipe<<<NB, NT, 0, stream>>>(x, h0i, c0i, wih0, whh0, bih0, bhh0,
                                     wih1, whh1, bih1, bhh1,
                                     wmean, bmean, wcrit, bcrit,
                                     (float*)d_out);
}